// Round 1
// 647.760 us; speedup vs baseline: 1.1720x; 1.1720x over previous
//
#include <hip/hip_runtime.h>
#include <cmath>

#define BB 4
#define NN 4096
#define CC 1024
#define HH 8
#define DD 128
#define MM (BB*NN)   // 16384
#define NP (NN+2)    // padded rows per batch

typedef __attribute__((ext_vector_type(8))) short bf16x8;
typedef __attribute__((ext_vector_type(4))) float f32x4;

static __device__ __forceinline__ unsigned short f2bf(float f) {
    unsigned int u = __float_as_uint(f);
    unsigned int r = (u + 0x7FFF + ((u >> 16) & 1)) >> 16;
    return (unsigned short)r;
}
static __device__ __forceinline__ float bf2f(short s) {
    return __uint_as_float(((unsigned int)(unsigned short)s) << 16);
}
static __device__ __forceinline__ float4 bf4(ushort4 u) {
    float4 f;
    f.x = __uint_as_float((unsigned int)u.x << 16);
    f.y = __uint_as_float((unsigned int)u.y << 16);
    f.z = __uint_as_float((unsigned int)u.z << 16);
    f.w = __uint_as_float((unsigned int)u.w << 16);
    return f;
}

static __device__ __forceinline__ void load_lds16(const void* g, void* l) {
    __builtin_amdgcn_global_load_lds(
        (const __attribute__((address_space(1))) unsigned int*)g,
        (__attribute__((address_space(3))) unsigned int*)l, 16, 0, 0);
}

// ---------------------------------------------------------------------------
// P1: xpad[b][p][c] (bf16), p in [0,NP): rows 0 and NP-1 zero, p = x[b][p-1]
// ---------------------------------------------------------------------------
__global__ __launch_bounds__(256) void padx_kernel(
    const float* __restrict__ x, unsigned short* __restrict__ xpad)
{
    const int r = blockIdx.x;
    const int b = r / NP, p = r % NP;
    const int c = threadIdx.x * 4;
    ushort4 v = {0, 0, 0, 0};
    if (p >= 1 && p <= NN) {
        const float4 f = *(const float4*)&x[(size_t)(b * NN + p - 1) * CC + c];
        v.x = f2bf(f.x); v.y = f2bf(f.y); v.z = f2bf(f.z); v.w = f2bf(f.w);
    }
    *(ushort4*)&xpad[(size_t)r * CC + c] = v;
}

// ---------------------------------------------------------------------------
// P2: dst[c][r] = bf16(src[r][c])
// ---------------------------------------------------------------------------
__global__ __launch_bounds__(256) void transpose_bf16_kernel(
    const float* __restrict__ src, unsigned short* __restrict__ dst,
    int R, int Cc)
{
    __shared__ float t[32][33];
    const int r0 = blockIdx.y * 32, c0 = blockIdx.x * 32;
    const int tx = threadIdx.x & 31, ty = threadIdx.x >> 5;
    #pragma unroll
    for (int i = 0; i < 4; ++i) {
        int r = ty + i * 8;
        t[r][tx] = src[(size_t)(r0 + r) * Cc + c0 + tx];
    }
    __syncthreads();
    #pragma unroll
    for (int i = 0; i < 4; ++i) {
        int r = ty + i * 8;
        dst[(size_t)(c0 + r) * R + r0 + tx] = f2bf(t[tx][r]);
    }
}

// ---------------------------------------------------------------------------
// Shared staging for the 256x256/BK=64 2-phase GEMMs:
// A-tile 256x64 bf16 (32KB) + B-tile 256x64 bf16 (32KB), row-major [256][64].
// chunk c = l*512 + tid: row = c>>3, col8 = c&7. LDS dest = wave-uniform base
// + lane*16 (global_load_lds constraint); global source is per-lane.
// ---------------------------------------------------------------------------
static __device__ __forceinline__ void stage_ab(
    const unsigned short* __restrict__ Ag, int astride,
    const unsigned short* __restrict__ Bg, int bstride,
    unsigned short* As, unsigned short* Bs, int tid)
{
    const int wb = tid & ~63;   // wave-uniform
    #pragma unroll
    for (int l = 0; l < 4; ++l) {
        const int c = l * 512 + tid;
        load_lds16(&Ag[(size_t)(c >> 3) * astride + (c & 7) * 8],
                   &As[(size_t)(l * 512 + wb) * 8]);
    }
    #pragma unroll
    for (int l = 0; l < 4; ++l) {
        const int c = l * 512 + tid;
        load_lds16(&Bg[(size_t)(c >> 3) * bstride + (c & 7) * 8],
                   &Bs[(size_t)(l * 512 + wb) * 8]);
    }
}

// ---------------------------------------------------------------------------
// K1: qk = x @ qk_w + qk_b ; elu+1 ; q,k stored bf16; k column sums -> ksum
// 256x256 tile, BK=64, 512 thr (8 waves, 2Mx4N), double-buffered LDS 128KB,
// 2-phase: stage(next) -> ds_read+MFMA(cur) -> __syncthreads (drains vmcnt).
// ---------------------------------------------------------------------------
__global__ __launch_bounds__(512) void gemm_qk_mfma(
    const unsigned short* __restrict__ xpad, const unsigned short* __restrict__ wT,
    const float* __restrict__ bias, unsigned short* __restrict__ qbuf,
    unsigned short* __restrict__ kbuf, float* __restrict__ ksum)
{
    __shared__ __align__(16) unsigned short As[2][16384];
    __shared__ __align__(16) unsigned short Bs[2][16384];
    const int m0 = blockIdx.x * 256;
    const int n0 = blockIdx.y * 256;
    const int tid = threadIdx.x;
    const int lane = tid & 63;
    const int wv = tid >> 6;
    const int wr = wv >> 2, wc = wv & 3;       // wave -> (M-half, N-quarter)
    const int b = m0 >> 12;
    const int rbase = m0 + 1 + 2 * b;          // padded-row base

    f32x4 acc[8][4] = {};
    stage_ab(&xpad[(size_t)rbase * CC], CC, &wT[(size_t)n0 * CC], CC,
             As[0], Bs[0], tid);
    __syncthreads();
    for (int kt = 0; kt < 16; ++kt) {
        const int cur = kt & 1;
        if (kt + 1 < 16)
            stage_ab(&xpad[(size_t)rbase * CC + (kt + 1) * 64], CC,
                     &wT[(size_t)n0 * CC + (kt + 1) * 64], CC,
                     As[cur ^ 1], Bs[cur ^ 1], tid);
        const unsigned short* Ab = As[cur];
        const unsigned short* Bb = Bs[cur];
        const int rl = lane & 15;
        #pragma unroll
        for (int ks = 0; ks < 2; ++ks) {
            const int ko = ks * 32 + (lane >> 4) * 8;
            bf16x8 af[8], bfr[4];
            #pragma unroll
            for (int mf = 0; mf < 8; ++mf)
                af[mf] = *(const bf16x8*)&Ab[(wr * 128 + mf * 16 + rl) * 64 + ko];
            #pragma unroll
            for (int nf = 0; nf < 4; ++nf)
                bfr[nf] = *(const bf16x8*)&Bb[(wc * 64 + nf * 16 + rl) * 64 + ko];
            #pragma unroll
            for (int mf = 0; mf < 8; ++mf)
                #pragma unroll
                for (int nf = 0; nf < 4; ++nf)
                    acc[mf][nf] = __builtin_amdgcn_mfma_f32_16x16x32_bf16(
                        af[mf], bfr[nf], acc[mf][nf], 0, 0, 0);
        }
        __syncthreads();   // drains vmcnt(0): next tile landed, cur free
    }
    const bool khalf = (n0 >= CC);             // block is entirely q or k half
    const int col = lane & 15, rb4 = (lane >> 4) * 4;
    #pragma unroll
    for (int nf = 0; nf < 4; ++nf) {
        const int n = n0 + wc * 64 + nf * 16 + col;
        const float bn = bias[n];
        float csum = 0.0f;
        #pragma unroll
        for (int mf = 0; mf < 8; ++mf)
            #pragma unroll
            for (int r = 0; r < 4; ++r) {
                const int m = m0 + wr * 128 + mf * 16 + rb4 + r;
                float v = acc[mf][nf][r] + bn;
                v = (v > 0.0f) ? (v + 1.0f) : expf(v);   // elu(v)+1
                csum += v;
                if (!khalf) qbuf[(size_t)m * CC + n] = f2bf(v);
                else        kbuf[(size_t)m * CC + (n - CC)] = f2bf(v);
            }
        if (khalf) atomicAdd(&ksum[b * CC + (n - CC)], csum);
    }
}

// ---------------------------------------------------------------------------
// K3: thread = (row, head). z[m,h] = 1/(dot(q_head, ksum_head)/N + 1e-6);
// RoPE q in place (barrier-ordered); kr -> krP[b][h][n][d] bf16.
// ---------------------------------------------------------------------------
__global__ __launch_bounds__(256) void rope_z_kernel(
    unsigned short* __restrict__ qbuf, const unsigned short* __restrict__ kbuf,
    const float* __restrict__ ksum, unsigned short* __restrict__ krP,
    float* __restrict__ zbuf)
{
    const int tid = threadIdx.x;
    const int row = tid >> 3;            // 0..31
    const int h = tid & 7;
    const int m = blockIdx.x * 32 + row;
    const int b = m >> 12;
    const int pos = m & (NN - 1);
    unsigned short* qrow = qbuf + (size_t)m * CC + h * DD;
    const unsigned short* krow = kbuf + (size_t)m * CC + h * DD;

    bf16x8 qv[16], kv8[16];
    #pragma unroll
    for (int i = 0; i < 16; ++i) {
        qv[i]  = *(const bf16x8*)&qrow[i * 8];
        kv8[i] = *(const bf16x8*)&krow[i * 8];
    }
    // z from pre-rope q
    const float* km = ksum + b * CC + h * DD;
    float dot = 0.0f;
    #pragma unroll
    for (int i = 0; i < 16; ++i)
        #pragma unroll
        for (int jq = 0; jq < 8; ++jq)
            dot = fmaf(bf2f(qv[i][jq]), km[i * 8 + jq], dot);
    dot *= (1.0f / (float)NN);
    __syncthreads();   // all q reads complete before in-place writes
    zbuf[(size_t)m * HH + h] = 1.0f / (dot + 1e-6f);

    #pragma unroll
    for (int c8 = 0; c8 < 8; ++c8) {
        bf16x8 qpr, qpi, kpr, kpi;
        #pragma unroll
        for (int u = 0; u < 8; ++u) {
            const int jj = c8 * 8 + u;
            const int j = h * 64 + jj;           // global pair index 0..511
            const float theta = __builtin_exp2f((float)j * (-13.287712379549449f / 512.0f));
            float sv, cv;
            sincosf((float)pos * theta, &sv, &cv);
            const int li = c8 * 2 + (u >> 2);
            const int le = (2 * u) & 7;
            const float q0 = bf2f(qv[li][le]),  q1 = bf2f(qv[li][le + 1]);
            const float k0 = bf2f(kv8[li][le]), k1 = bf2f(kv8[li][le + 1]);
            qpr[u] = (short)f2bf(cv * q0 - sv * q1);
            qpi[u] = (short)f2bf(cv * q1 + sv * q0);
            kpr[u] = (short)f2bf(cv * k0 - sv * k1);
            kpi[u] = (short)f2bf(cv * k1 + sv * k0);
        }
        *(bf16x8*)&qbuf[(size_t)m * CC + h * 64 + c8 * 8] = qpr;
        *(bf16x8*)&qbuf[(size_t)m * CC + 512 + h * 64 + c8 * 8] = qpi;
        unsigned short* kp1 = &krP[((size_t)(b * 8 + (h >> 1)) * NN + pos) * DD + (h & 1) * 64 + c8 * 8];
        unsigned short* kp2 = &krP[((size_t)(b * 8 + 4 + (h >> 1)) * NN + pos) * DD + (h & 1) * 64 + c8 * 8];
        *(bf16x8*)kp1 = kpr;
        *(bf16x8*)kp2 = kpi;
    }
}

// ---------------------------------------------------------------------------
// K4: kvpart[slice][bh][d][e] = sum over slice's 256 n of kr[n,d]*v[n,e]
// ---------------------------------------------------------------------------
__global__ __launch_bounds__(256) void kv_kernel(
    const unsigned short* __restrict__ krP, const unsigned short* __restrict__ xpad,
    float* __restrict__ kvpart)
{
    __shared__ float ksm[8][132];
    __shared__ float vsm[8][132];
    const int bh = blockIdx.x;                 // 0..31
    const int slice = blockIdx.y;              // 0..15
    const int b = bh >> 3, h = bh & 7;
    const int n0 = slice * 256;
    const int tid = threadIdx.x;
    const int td = (tid >> 4) * 8;
    const int te = (tid & 15) * 8;
    const unsigned short* kp = krP + ((size_t)bh * NN + n0) * DD;
    const unsigned short* vp = xpad + ((size_t)(b * NP) + 1 + n0) * CC + h * DD;
    const int sr = tid >> 5;                   // staging row 0..7
    const int sc = (tid & 31) * 4;             // staging col
    float acc[8][8] = {};
    for (int r0 = 0; r0 < 256; r0 += 8) {
        const ushort4 kq = *(const ushort4*)&kp[(size_t)(r0 + sr) * DD + sc];
        const ushort4 vq = *(const ushort4*)&vp[(size_t)(r0 + sr) * CC + sc];
        *(float4*)&ksm[sr][sc] = bf4(kq);
        *(float4*)&vsm[sr][sc] = bf4(vq);
        __syncthreads();
        #pragma unroll
        for (int r = 0; r < 8; ++r) {
            float a[8], bv[8];
            *(float4*)&a[0]  = *(const float4*)&ksm[r][td];
            *(float4*)&a[4]  = *(const float4*)&ksm[r][td + 4];
            *(float4*)&bv[0] = *(const float4*)&vsm[r][te];
            *(float4*)&bv[4] = *(const float4*)&vsm[r][te + 4];
            #pragma unroll
            for (int i = 0; i < 8; ++i)
                #pragma unroll
                for (int j = 0; j < 8; ++j)
                    acc[i][j] = fmaf(a[i], bv[j], acc[i][j]);
        }
        __syncthreads();
    }
    float* op = kvpart + ((size_t)slice * 32 + bh) * (DD * DD);
    #pragma unroll
    for (int i = 0; i < 8; ++i)
        #pragma unroll
        for (int j = 0; j < 8; j += 4)
            *(float4*)&op[(td + i) * DD + te + j] = *(float4*)&acc[i][j];
}

// ---------------------------------------------------------------------------
// K4b: kvred = (1/64) * sum over 16 slices
// ---------------------------------------------------------------------------
__global__ __launch_bounds__(256) void kv_reduce_kernel(
    const float* __restrict__ kvpart, float* __restrict__ kvred)
{
    const size_t i = ((size_t)blockIdx.x * 256 + threadIdx.x) * 4;
    float4 s = {0.0f, 0.0f, 0.0f, 0.0f};
    #pragma unroll
    for (int sl = 0; sl < 16; ++sl) {
        const float4 v = *(const float4*)&kvpart[(size_t)sl * (32 * DD * DD) + i];
        s.x += v.x; s.y += v.y; s.z += v.z; s.w += v.w;
    }
    s.x *= (1.0f / 64.0f); s.y *= (1.0f / 64.0f);
    s.z *= (1.0f / 64.0f); s.w *= (1.0f / 64.0f);
    *(float4*)&kvred[i] = s;
}

// ---------------------------------------------------------------------------
// K5: out[m, h*128+e] = z[m,h] * sum_d qr[m,h*128+d] * kv[b,h,d,e]
// ---------------------------------------------------------------------------
__global__ __launch_bounds__(256) void attn_out_kernel(
    const unsigned short* __restrict__ qr, const float* __restrict__ kv,
    const float* __restrict__ z, float* __restrict__ out)
{
    __shared__ float qsm[16][68];
    __shared__ float kvs[16][128];
    const int m0 = blockIdx.x * 64;
    const int h = blockIdx.y;
    const int b = m0 >> 12;
    const int tid = threadIdx.x;
    const int tm = (tid >> 4) * 4;
    const int tn = (tid & 15) * 8;
    const unsigned short* qp = qr + (size_t)m0 * CC + h * DD;
    const float* kvp = kv + (size_t)(b * HH + h) * DD * DD;
    float acc[4][8] = {};
    for (int k0 = 0; k0 < DD; k0 += 16) {
        #pragma unroll
        for (int i = 0; i < 4; ++i) {
            int e = tid + i * 256;
            int r = e >> 4, c = e & 15;
            qsm[c][r] = bf2f(qp[(size_t)r * CC + k0 + c]);
        }
        #pragma unroll
        for (int i = 0; i < 8; ++i) {
            int e = tid + i * 256;
            int r = e >> 7, c = e & 127;
            kvs[r][c] = kvp[(k0 + r) * DD + c];
        }
        __syncthreads();
        #pragma unroll
        for (int kk = 0; kk < 16; ++kk) {
            float a[4], bv[8];
            *(float4*)&a[0]  = *(const float4*)&qsm[kk][tm];
            *(float4*)&bv[0] = *(const float4*)&kvs[kk][tn];
            *(float4*)&bv[4] = *(const float4*)&kvs[kk][tn + 4];
            #pragma unroll
            for (int i = 0; i < 4; ++i)
                #pragma unroll
                for (int j = 0; j < 8; ++j)
                    acc[i][j] = fmaf(a[i], bv[j], acc[i][j]);
        }
        __syncthreads();
    }
    #pragma unroll
    for (int i = 0; i < 4; ++i) {
        const int m = m0 + tm + i;
        const float zz = z[(size_t)m * HH + h];
        #pragma unroll
        for (int j = 0; j < 8; ++j)
            out[(size_t)m * CC + h * DD + tn + j] = acc[i][j] * zz;
    }
}

// ---------------------------------------------------------------------------
// K6: out += conv1d(x, lepe_w, SAME) + lepe_b   (implicit GEMM, bf16 MFMA)
// 256x256 tile, BK=64, 2-phase double-buffered (same structure as K1).
// K = 3*CC: K-tile kt covers cols [kt*64, kt*64+64) of the [shift][C] space;
// each BK=64 tile lies within one shift segment (1024 % 64 == 0).
// ---------------------------------------------------------------------------
__global__ __launch_bounds__(512) void lepe_mfma(
    const unsigned short* __restrict__ xpad, const unsigned short* __restrict__ wT,
    const float* __restrict__ bias, float* __restrict__ out)
{
    __shared__ __align__(16) unsigned short As[2][16384];
    __shared__ __align__(16) unsigned short Bs[2][16384];
    const int m0 = blockIdx.x * 256;
    const int n0 = blockIdx.y * 256;
    const int tid = threadIdx.x;
    const int lane = tid & 63;
    const int wv = tid >> 6;
    const int wr = wv >> 2, wc = wv & 3;
    const int b = m0 >> 12;
    const int rbase = m0 + 1 + 2 * b;

    f32x4 acc[8][4] = {};
    // kt=0: shift=-1, i0=0
    stage_ab(&xpad[(size_t)(rbase - 1) * CC], CC, &wT[(size_t)n0 * (3 * CC)], 3 * CC,
             As[0], Bs[0], tid);
    __syncthreads();
    for (int kt = 0; kt < 48; ++kt) {
        const int cur = kt & 1;
        if (kt + 1 < 48) {
            const int k0n = (kt + 1) * 64;
            const int sh = (k0n >> 10) - 1;
            const int i0 = k0n & (CC - 1);
            stage_ab(&xpad[(size_t)(rbase + sh) * CC + i0], CC,
                     &wT[(size_t)n0 * (3 * CC) + k0n], 3 * CC,
                     As[cur ^ 1], Bs[cur ^ 1], tid);
        }
        const unsigned short* Ab = As[cur];
        const unsigned short* Bb = Bs[cur];
        const int rl = lane & 15;
        #pragma unroll
        for (int ks = 0; ks < 2; ++ks) {
            const int ko = ks * 32 + (lane >> 4) * 8;
            bf16x8 af[8], bfr[4];
            #pragma unroll
            for (int mf = 0; mf < 8; ++mf)
                af[mf] = *(const bf16x8*)&Ab[(wr * 128 + mf * 16 + rl) * 64 + ko];
            #pragma unroll
            for (int nf = 0; nf < 4; ++nf)
                bfr[nf] = *(const bf16x8*)&Bb[(wc * 64 + nf * 16 + rl) * 64 + ko];
            #pragma unroll
            for (int mf = 0; mf < 8; ++mf)
                #pragma unroll
                for (int nf = 0; nf < 4; ++nf)
                    acc[mf][nf] = __builtin_amdgcn_mfma_f32_16x16x32_bf16(
                        af[mf], bfr[nf], acc[mf][nf], 0, 0, 0);
        }
        __syncthreads();
    }
    const int col = lane & 15, rb4 = (lane >> 4) * 4;
    #pragma unroll
    for (int nf = 0; nf < 4; ++nf) {
        const int n = n0 + wc * 64 + nf * 16 + col;
        const float bn = bias[n];
        #pragma unroll
        for (int mf = 0; mf < 8; ++mf)
            #pragma unroll
            for (int r = 0; r < 4; ++r) {
                const int m = m0 + wr * 128 + mf * 16 + rb4 + r;
                out[(size_t)m * CC + n] += acc[mf][nf][r] + bn;
            }
    }
}

// ---------------------------------------------------------------------------
extern "C" void kernel_launch(void* const* d_in, const int* in_sizes, int n_in,
                              void* d_out, int out_size, void* d_ws, size_t ws_size,
                              hipStream_t stream)
{
    const float* x      = (const float*)d_in[0];
    const float* qk_w   = (const float*)d_in[1];
    const float* qk_b   = (const float*)d_in[2];
    const float* lepe_w = (const float*)d_in[3];
    const float* lepe_b = (const float*)d_in[4];
    float* out = (float*)d_out;

    // fp32 region
    float* ws     = (float*)d_ws;
    float* zbuf   = ws;                                   // MM*HH
    float* ksum   = zbuf + (size_t)MM * HH;               // BB*CC
    float* kvred  = ksum + (size_t)BB * CC;               // 32*128*128
    float* kvpart = kvred + (size_t)32 * DD * DD;         // 16*32*128*128
    // bf16 region
    unsigned short* xpad = (unsigned short*)(kvpart + (size_t)16 * 32 * DD * DD);
    unsigned short* wqT  = xpad + (size_t)BB * NP * CC;   // [2048][1024]
    unsigned short* wlT  = wqT + (size_t)2 * CC * CC;     // [1024][3072]
    unsigned short* qbuf = wlT + (size_t)CC * 3 * CC;     // M*C (q, then qr in place)
    unsigned short* kbuf = qbuf + (size_t)MM * CC;        // M*C
    unsigned short* krP  = kbuf + (size_t)MM * CC;        // [32][4096][128]

    hipMemsetAsync(ksum, 0, BB * CC * sizeof(float), stream);

    padx_kernel          <<<BB * NP,                      256, 0, stream>>>(x, xpad);
    transpose_bf16_kernel<<<dim3(2 * CC / 32, CC / 32),   256, 0, stream>>>(qk_w, wqT, CC, 2 * CC);
    transpose_bf16_kernel<<<dim3(CC / 32, 3 * CC / 32),   256, 0, stream>>>(lepe_w, wlT, 3 * CC, CC);

    gemm_qk_mfma    <<<dim3(MM / 256, 2048 / 256), 512, 0, stream>>>(xpad, wqT, qk_b, qbuf, kbuf, ksum);
    rope_z_kernel   <<<MM / 32,                    256, 0, stream>>>(qbuf, kbuf, ksum, krP, zbuf);
    kv_kernel       <<<dim3(32, 16),               256, 0, stream>>>(krP, xpad, kvpart);
    kv_reduce_kernel<<<(32 * DD * DD / 4) / 256,   256, 0, stream>>>(kvpart, kvred);
    attn_out_kernel <<<dim3(MM / 64, HH),          256, 0, stream>>>(qbuf, kvred, zbuf, out);
    lepe_mfma       <<<dim3(MM / 256, CC / 256),   512, 0, stream>>>(xpad, wlT, lepe_b, out);
}

// Round 2
// 550.963 us; speedup vs baseline: 1.3779x; 1.1757x over previous
//
#include <hip/hip_runtime.h>
#include <cmath>

#define BB 4
#define NN 4096
#define CC 1024
#define HH 8
#define DD 128
#define MM (BB*NN)   // 16384
#define NP (NN+2)    // padded rows per batch

typedef __attribute__((ext_vector_type(8))) short bf16x8;
typedef __attribute__((ext_vector_type(4))) float f32x4;

static __device__ __forceinline__ unsigned short f2bf(float f) {
    unsigned int u = __float_as_uint(f);
    unsigned int r = (u + 0x7FFF + ((u >> 16) & 1)) >> 16;
    return (unsigned short)r;
}
static __device__ __forceinline__ float bf2f(short s) {
    return __uint_as_float(((unsigned int)(unsigned short)s) << 16);
}
static __device__ __forceinline__ float4 bf4(ushort4 u) {
    float4 f;
    f.x = __uint_as_float((unsigned int)u.x << 16);
    f.y = __uint_as_float((unsigned int)u.y << 16);
    f.z = __uint_as_float((unsigned int)u.z << 16);
    f.w = __uint_as_float((unsigned int)u.w << 16);
    return f;
}

static __device__ __forceinline__ void load_lds16(const void* g, void* l) {
    __builtin_amdgcn_global_load_lds(
        (const __attribute__((address_space(1))) unsigned int*)g,
        (__attribute__((address_space(3))) unsigned int*)l, 16, 0, 0);
}

// ---------------------------------------------------------------------------
// P1: xpad[b][p][c] (bf16), p in [0,NP): rows 0 and NP-1 zero, p = x[b][p-1]
// ---------------------------------------------------------------------------
__global__ __launch_bounds__(256) void padx_kernel(
    const float* __restrict__ x, unsigned short* __restrict__ xpad)
{
    const int r = blockIdx.x;
    const int b = r / NP, p = r % NP;
    const int c = threadIdx.x * 4;
    ushort4 v = {0, 0, 0, 0};
    if (p >= 1 && p <= NN) {
        const float4 f = *(const float4*)&x[(size_t)(b * NN + p - 1) * CC + c];
        v.x = f2bf(f.x); v.y = f2bf(f.y); v.z = f2bf(f.z); v.w = f2bf(f.w);
    }
    *(ushort4*)&xpad[(size_t)r * CC + c] = v;
}

// ---------------------------------------------------------------------------
// P2: dst[c][r] = bf16(src[r][c])
// ---------------------------------------------------------------------------
__global__ __launch_bounds__(256) void transpose_bf16_kernel(
    const float* __restrict__ src, unsigned short* __restrict__ dst,
    int R, int Cc)
{
    __shared__ float t[32][33];
    const int r0 = blockIdx.y * 32, c0 = blockIdx.x * 32;
    const int tx = threadIdx.x & 31, ty = threadIdx.x >> 5;
    #pragma unroll
    for (int i = 0; i < 4; ++i) {
        int r = ty + i * 8;
        t[r][tx] = src[(size_t)(r0 + r) * Cc + c0 + tx];
    }
    __syncthreads();
    #pragma unroll
    for (int i = 0; i < 4; ++i) {
        int r = ty + i * 8;
        dst[(size_t)(c0 + r) * R + r0 + tx] = f2bf(t[tx][r]);
    }
}

// ---------------------------------------------------------------------------
// Staging helpers for 256x64 bf16 tiles (512 threads, 4 x 16B loads each).
// LDS dest is wave-uniform base + lane*16 (global_load_lds constraint);
// global source address is per-lane.
// ---------------------------------------------------------------------------
static __device__ __forceinline__ void stage_tile(
    const unsigned short* __restrict__ g, int stride,
    unsigned short* lds, int tid)
{
    const int wb = tid & ~63;   // wave-uniform
    #pragma unroll
    for (int l = 0; l < 4; ++l) {
        const int c = l * 512 + tid;
        load_lds16(&g[(size_t)(c >> 3) * stride + (c & 7) * 8],
                   &lds[(size_t)(l * 512 + wb) * 8]);
    }
}
static __device__ __forceinline__ void stage_ab(
    const unsigned short* __restrict__ Ag, int astride,
    const unsigned short* __restrict__ Bg, int bstride,
    unsigned short* As, unsigned short* Bs, int tid)
{
    stage_tile(Ag, astride, As, tid);
    stage_tile(Bg, bstride, Bs, tid);
}

// ---------------------------------------------------------------------------
// K1: qk = x @ qk_w + qk_b ; elu+1 ; q,k stored bf16; k column sums -> ksum
// 256x256 tile, BK=64, 512 thr (8 waves, 2Mx4N), double-buffered LDS 128KB,
// 2-phase: stage(next) -> ds_read+MFMA(cur) -> __syncthreads (drains vmcnt).
// ---------------------------------------------------------------------------
__global__ __launch_bounds__(512) void gemm_qk_mfma(
    const unsigned short* __restrict__ xpad, const unsigned short* __restrict__ wT,
    const float* __restrict__ bias, unsigned short* __restrict__ qbuf,
    unsigned short* __restrict__ kbuf, float* __restrict__ ksum)
{
    __shared__ __align__(16) unsigned short As[2][16384];
    __shared__ __align__(16) unsigned short Bs[2][16384];
    const int m0 = blockIdx.x * 256;
    const int n0 = blockIdx.y * 256;
    const int tid = threadIdx.x;
    const int lane = tid & 63;
    const int wv = tid >> 6;
    const int wr = wv >> 2, wc = wv & 3;       // wave -> (M-half, N-quarter)
    const int b = m0 >> 12;
    const int rbase = m0 + 1 + 2 * b;          // padded-row base
    const int rl = lane & 15;

    f32x4 acc[8][4] = {};
    stage_ab(&xpad[(size_t)rbase * CC], CC, &wT[(size_t)n0 * CC], CC,
             As[0], Bs[0], tid);
    __syncthreads();
    for (int kt = 0; kt < 16; ++kt) {
        const int cur = kt & 1;
        if (kt + 1 < 16)
            stage_ab(&xpad[(size_t)rbase * CC + (kt + 1) * 64], CC,
                     &wT[(size_t)n0 * CC + (kt + 1) * 64], CC,
                     As[cur ^ 1], Bs[cur ^ 1], tid);
        const unsigned short* Ab = As[cur];
        const unsigned short* Bb = Bs[cur];
        #pragma unroll
        for (int ks = 0; ks < 2; ++ks) {
            const int ko = ks * 32 + (lane >> 4) * 8;
            bf16x8 af[8], bfr[4];
            #pragma unroll
            for (int mf = 0; mf < 8; ++mf)
                af[mf] = *(const bf16x8*)&Ab[(wr * 128 + mf * 16 + rl) * 64 + ko];
            #pragma unroll
            for (int nf = 0; nf < 4; ++nf)
                bfr[nf] = *(const bf16x8*)&Bb[(wc * 64 + nf * 16 + rl) * 64 + ko];
            #pragma unroll
            for (int mf = 0; mf < 8; ++mf)
                #pragma unroll
                for (int nf = 0; nf < 4; ++nf)
                    acc[mf][nf] = __builtin_amdgcn_mfma_f32_16x16x32_bf16(
                        af[mf], bfr[nf], acc[mf][nf], 0, 0, 0);
        }
        __syncthreads();   // drains vmcnt(0): next tile landed, cur free
    }
    const bool khalf = (n0 >= CC);             // block is entirely q or k half
    const int col = lane & 15, rb4 = (lane >> 4) * 4;
    #pragma unroll
    for (int nf = 0; nf < 4; ++nf) {
        const int n = n0 + wc * 64 + nf * 16 + col;
        const float bn = bias[n];
        float csum = 0.0f;
        #pragma unroll
        for (int mf = 0; mf < 8; ++mf)
            #pragma unroll
            for (int r = 0; r < 4; ++r) {
                const int m = m0 + wr * 128 + mf * 16 + rb4 + r;
                float v = acc[mf][nf][r] + bn;
                v = (v > 0.0f) ? (v + 1.0f) : expf(v);   // elu(v)+1
                csum += v;
                if (!khalf) qbuf[(size_t)m * CC + n] = f2bf(v);
                else        kbuf[(size_t)m * CC + (n - CC)] = f2bf(v);
            }
        if (khalf) atomicAdd(&ksum[b * CC + (n - CC)], csum);
    }
}

// ---------------------------------------------------------------------------
// K3: thread = (row, head). z[m,h] = 1/(dot(q_head, ksum_head)/N + 1e-6);
// RoPE q in place (barrier-ordered); kr -> krP[b][h][n][d] bf16.
// ---------------------------------------------------------------------------
__global__ __launch_bounds__(256) void rope_z_kernel(
    unsigned short* __restrict__ qbuf, const unsigned short* __restrict__ kbuf,
    const float* __restrict__ ksum, unsigned short* __restrict__ krP,
    float* __restrict__ zbuf)
{
    const int tid = threadIdx.x;
    const int row = tid >> 3;            // 0..31
    const int h = tid & 7;
    const int m = blockIdx.x * 32 + row;
    const int b = m >> 12;
    const int pos = m & (NN - 1);
    unsigned short* qrow = qbuf + (size_t)m * CC + h * DD;
    const unsigned short* krow = kbuf + (size_t)m * CC + h * DD;

    bf16x8 qv[16], kv8[16];
    #pragma unroll
    for (int i = 0; i < 16; ++i) {
        qv[i]  = *(const bf16x8*)&qrow[i * 8];
        kv8[i] = *(const bf16x8*)&krow[i * 8];
    }
    // z from pre-rope q
    const float* km = ksum + b * CC + h * DD;
    float dot = 0.0f;
    #pragma unroll
    for (int i = 0; i < 16; ++i)
        #pragma unroll
        for (int jq = 0; jq < 8; ++jq)
            dot = fmaf(bf2f(qv[i][jq]), km[i * 8 + jq], dot);
    dot *= (1.0f / (float)NN);
    __syncthreads();   // all q reads complete before in-place writes
    zbuf[(size_t)m * HH + h] = 1.0f / (dot + 1e-6f);

    #pragma unroll
    for (int c8 = 0; c8 < 8; ++c8) {
        bf16x8 qpr, qpi, kpr, kpi;
        #pragma unroll
        for (int u = 0; u < 8; ++u) {
            const int jj = c8 * 8 + u;
            const int j = h * 64 + jj;           // global pair index 0..511
            const float theta = __builtin_exp2f((float)j * (-13.287712379549449f / 512.0f));
            float sv, cv;
            __sincosf((float)pos * theta, &sv, &cv);
            const int li = c8 * 2 + (u >> 2);
            const int le = (2 * u) & 7;
            const float q0 = bf2f(qv[li][le]),  q1 = bf2f(qv[li][le + 1]);
            const float k0 = bf2f(kv8[li][le]), k1 = bf2f(kv8[li][le + 1]);
            qpr[u] = (short)f2bf(cv * q0 - sv * q1);
            qpi[u] = (short)f2bf(cv * q1 + sv * q0);
            kpr[u] = (short)f2bf(cv * k0 - sv * k1);
            kpi[u] = (short)f2bf(cv * k1 + sv * k0);
        }
        *(bf16x8*)&qbuf[(size_t)m * CC + h * 64 + c8 * 8] = qpr;
        *(bf16x8*)&qbuf[(size_t)m * CC + 512 + h * 64 + c8 * 8] = qpi;
        unsigned short* kp1 = &krP[((size_t)(b * 8 + (h >> 1)) * NN + pos) * DD + (h & 1) * 64 + c8 * 8];
        unsigned short* kp2 = &krP[((size_t)(b * 8 + 4 + (h >> 1)) * NN + pos) * DD + (h & 1) * 64 + c8 * 8];
        *(bf16x8*)kp1 = kpr;
        *(bf16x8*)kp2 = kpi;
    }
}

// ---------------------------------------------------------------------------
// K4: kvpart[slice][bh][d][e] = sum over slice's 256 n of kr[n,d]*v[n,e]
// ---------------------------------------------------------------------------
__global__ __launch_bounds__(256) void kv_kernel(
    const unsigned short* __restrict__ krP, const unsigned short* __restrict__ xpad,
    float* __restrict__ kvpart)
{
    __shared__ float ksm[8][132];
    __shared__ float vsm[8][132];
    const int bh = blockIdx.x;                 // 0..31
    const int slice = blockIdx.y;              // 0..15
    const int b = bh >> 3, h = bh & 7;
    const int n0 = slice * 256;
    const int tid = threadIdx.x;
    const int td = (tid >> 4) * 8;
    const int te = (tid & 15) * 8;
    const unsigned short* kp = krP + ((size_t)bh * NN + n0) * DD;
    const unsigned short* vp = xpad + ((size_t)(b * NP) + 1 + n0) * CC + h * DD;
    const int sr = tid >> 5;                   // staging row 0..7
    const int sc = (tid & 31) * 4;             // staging col
    float acc[8][8] = {};
    for (int r0 = 0; r0 < 256; r0 += 8) {
        const ushort4 kq = *(const ushort4*)&kp[(size_t)(r0 + sr) * DD + sc];
        const ushort4 vq = *(const ushort4*)&vp[(size_t)(r0 + sr) * CC + sc];
        *(float4*)&ksm[sr][sc] = bf4(kq);
        *(float4*)&vsm[sr][sc] = bf4(vq);
        __syncthreads();
        #pragma unroll
        for (int r = 0; r < 8; ++r) {
            float a[8], bv[8];
            *(float4*)&a[0]  = *(const float4*)&ksm[r][td];
            *(float4*)&a[4]  = *(const float4*)&ksm[r][td + 4];
            *(float4*)&bv[0] = *(const float4*)&vsm[r][te];
            *(float4*)&bv[4] = *(const float4*)&vsm[r][te + 4];
            #pragma unroll
            for (int i = 0; i < 8; ++i)
                #pragma unroll
                for (int j = 0; j < 8; ++j)
                    acc[i][j] = fmaf(a[i], bv[j], acc[i][j]);
        }
        __syncthreads();
    }
    float* op = kvpart + ((size_t)slice * 32 + bh) * (DD * DD);
    #pragma unroll
    for (int i = 0; i < 8; ++i)
        #pragma unroll
        for (int j = 0; j < 8; j += 4)
            *(float4*)&op[(td + i) * DD + te + j] = *(float4*)&acc[i][j];
}

// ---------------------------------------------------------------------------
// K4b: kvT[bh][e][d] = bf16( (1/64) * sum over 16 slices kvpart[sl][bh][d][e] )
// 32x32 LDS-transposed tiles; grid (16 tiles, 32 bh).
// ---------------------------------------------------------------------------
__global__ __launch_bounds__(256) void kv_reduce_t_kernel(
    const float* __restrict__ kvpart, unsigned short* __restrict__ kvT)
{
    __shared__ float t[32][33];
    const int bh = blockIdx.y;
    const int dblk = blockIdx.x >> 2, eblk = blockIdx.x & 3;
    const int tx = threadIdx.x & 31, ty = threadIdx.x >> 5;
    #pragma unroll
    for (int i = 0; i < 4; ++i) {
        const int d = dblk * 32 + ty + i * 8;
        float s = 0.0f;
        #pragma unroll
        for (int sl = 0; sl < 16; ++sl)
            s += kvpart[((size_t)sl * 32 + bh) * (DD * DD) + (size_t)d * DD + eblk * 32 + tx];
        t[ty + i * 8][tx] = s * (1.0f / 64.0f);
    }
    __syncthreads();
    #pragma unroll
    for (int i = 0; i < 4; ++i) {
        const int e = ty + i * 8;
        kvT[((size_t)bh * DD + eblk * 32 + e) * DD + dblk * 32 + tx] = f2bf(t[tx][e]);
    }
}

// ---------------------------------------------------------------------------
// K6 (fused): out = z * (qr @ kv) + conv1d(x, lepe_w, SAME) + lepe_b
// attn pre-pass: 2 K-tiles (K=128 head dim), A per head-half of the n-block
// (As[0]=head h0, As[1]=head h0+1), B = kvT rows [h0*128 .. h0*128+255].
// Then acc *= z[m,h]; then 48-tile conv loop accumulates on top.
// Epilogue is a pure store (no out RMW).
// ---------------------------------------------------------------------------
__global__ __launch_bounds__(512) void lepe_mfma(
    const unsigned short* __restrict__ xpad, const unsigned short* __restrict__ wT,
    const float* __restrict__ bias, const unsigned short* __restrict__ qr,
    const unsigned short* __restrict__ kvT, const float* __restrict__ z,
    float* __restrict__ out)
{
    __shared__ __align__(16) unsigned short As[2][16384];
    __shared__ __align__(16) unsigned short Bs[2][16384];
    const int m0 = blockIdx.x * 256;
    const int n0 = blockIdx.y * 256;
    const int tid = threadIdx.x;
    const int lane = tid & 63;
    const int wv = tid >> 6;
    const int wr = wv >> 2, wc = wv & 3;
    const int b = m0 >> 12;
    const int rbase = m0 + 1 + 2 * b;
    const int rl = lane & 15;
    const int rb4 = (lane >> 4) * 4;
    const int h0 = n0 >> 7;                    // first head of this n-block
    const int hw = h0 + (wc >> 1);             // wave's head (wave-uniform)

    f32x4 acc[8][4] = {};

    // ---- attn pre-pass: acc = qr(m, head cols) @ kvT^T over K=128 ----
    #pragma unroll
    for (int kt = 0; kt < 2; ++kt) {
        stage_tile(&qr[(size_t)m0 * CC + h0 * DD + kt * 64], CC, As[0], tid);
        stage_tile(&qr[(size_t)m0 * CC + (h0 + 1) * DD + kt * 64], CC, As[1], tid);
        stage_tile(&kvT[(size_t)(b * 8 + h0) * DD * DD + kt * 64], DD, Bs[0], tid);
        __syncthreads();
        const unsigned short* Ab = As[wc >> 1];
        const unsigned short* Bb = Bs[0];
        #pragma unroll
        for (int ks = 0; ks < 2; ++ks) {
            const int ko = ks * 32 + (lane >> 4) * 8;
            bf16x8 af[8], bfr[4];
            #pragma unroll
            for (int mf = 0; mf < 8; ++mf)
                af[mf] = *(const bf16x8*)&Ab[(wr * 128 + mf * 16 + rl) * 64 + ko];
            #pragma unroll
            for (int nf = 0; nf < 4; ++nf)
                bfr[nf] = *(const bf16x8*)&Bb[(wc * 64 + nf * 16 + rl) * 64 + ko];
            #pragma unroll
            for (int mf = 0; mf < 8; ++mf)
                #pragma unroll
                for (int nf = 0; nf < 4; ++nf)
                    acc[mf][nf] = __builtin_amdgcn_mfma_f32_16x16x32_bf16(
                        af[mf], bfr[nf], acc[mf][nf], 0, 0, 0);
        }
        __syncthreads();
    }

    // ---- scale attn accumulator by z[m, hw] ----
    #pragma unroll
    for (int mf = 0; mf < 8; ++mf)
        #pragma unroll
        for (int r = 0; r < 4; ++r) {
            const float zz = z[(size_t)(m0 + wr * 128 + mf * 16 + rb4 + r) * HH + hw];
            #pragma unroll
            for (int nf = 0; nf < 4; ++nf)
                acc[mf][nf][r] *= zz;
        }

    // ---- conv main loop (2-phase double-buffered) ----
    // kt=0: shift=-1, i0=0
    stage_ab(&xpad[(size_t)(rbase - 1) * CC], CC, &wT[(size_t)n0 * (3 * CC)], 3 * CC,
             As[0], Bs[0], tid);
    __syncthreads();
    for (int kt = 0; kt < 48; ++kt) {
        const int cur = kt & 1;
        if (kt + 1 < 48) {
            const int k0n = (kt + 1) * 64;
            const int sh = (k0n >> 10) - 1;
            const int i0 = k0n & (CC - 1);
            stage_ab(&xpad[(size_t)(rbase + sh) * CC + i0], CC,
                     &wT[(size_t)n0 * (3 * CC) + k0n], 3 * CC,
                     As[cur ^ 1], Bs[cur ^ 1], tid);
        }
        const unsigned short* Ab = As[cur];
        const unsigned short* Bb = Bs[cur];
        #pragma unroll
        for (int ks = 0; ks < 2; ++ks) {
            const int ko = ks * 32 + (lane >> 4) * 8;
            bf16x8 af[8], bfr[4];
            #pragma unroll
            for (int mf = 0; mf < 8; ++mf)
                af[mf] = *(const bf16x8*)&Ab[(wr * 128 + mf * 16 + rl) * 64 + ko];
            #pragma unroll
            for (int nf = 0; nf < 4; ++nf)
                bfr[nf] = *(const bf16x8*)&Bb[(wc * 64 + nf * 16 + rl) * 64 + ko];
            #pragma unroll
            for (int mf = 0; mf < 8; ++mf)
                #pragma unroll
                for (int nf = 0; nf < 4; ++nf)
                    acc[mf][nf] = __builtin_amdgcn_mfma_f32_16x16x32_bf16(
                        af[mf], bfr[nf], acc[mf][nf], 0, 0, 0);
        }
        __syncthreads();
    }

    // ---- epilogue: pure write ----
    const int col = lane & 15;
    #pragma unroll
    for (int nf = 0; nf < 4; ++nf) {
        const int n = n0 + wc * 64 + nf * 16 + col;
        const float bn = bias[n];
        #pragma unroll
        for (int mf = 0; mf < 8; ++mf)
            #pragma unroll
            for (int r = 0; r < 4; ++r) {
                const int m = m0 + wr * 128 + mf * 16 + rb4 + r;
                out[(size_t)m * CC + n] = acc[mf][nf][r] + bn;
            }
    }
}

// ---------------------------------------------------------------------------
extern "C" void kernel_launch(void* const* d_in, const int* in_sizes, int n_in,
                              void* d_out, int out_size, void* d_ws, size_t ws_size,
                              hipStream_t stream)
{
    const float* x      = (const float*)d_in[0];
    const float* qk_w   = (const float*)d_in[1];
    const float* qk_b   = (const float*)d_in[2];
    const float* lepe_w = (const float*)d_in[3];
    const float* lepe_b = (const float*)d_in[4];
    float* out = (float*)d_out;

    // fp32 region
    float* ws     = (float*)d_ws;
    float* zbuf   = ws;                                   // MM*HH
    float* ksum   = zbuf + (size_t)MM * HH;               // BB*CC
    float* kvpart = ksum + (size_t)BB * CC;               // 16*32*128*128
    // bf16 region
    unsigned short* xpad = (unsigned short*)(kvpart + (size_t)16 * 32 * DD * DD);
    unsigned short* wqT  = xpad + (size_t)BB * NP * CC;   // [2048][1024]
    unsigned short* wlT  = wqT + (size_t)2 * CC * CC;     // [1024][3072]
    unsigned short* qbuf = wlT + (size_t)CC * 3 * CC;     // M*C (q, then qr in place)
    unsigned short* kbuf = qbuf + (size_t)MM * CC;        // M*C
    unsigned short* krP  = kbuf + (size_t)MM * CC;        // [32][4096][128]
    unsigned short* kvT  = krP + (size_t)32 * NN * DD;    // [32][128e][128d]

    hipMemsetAsync(ksum, 0, BB * CC * sizeof(float), stream);

    padx_kernel          <<<BB * NP,                      256, 0, stream>>>(x, xpad);
    transpose_bf16_kernel<<<dim3(2 * CC / 32, CC / 32),   256, 0, stream>>>(qk_w, wqT, CC, 2 * CC);
    transpose_bf16_kernel<<<dim3(CC / 32, 3 * CC / 32),   256, 0, stream>>>(lepe_w, wlT, 3 * CC, CC);

    gemm_qk_mfma      <<<dim3(MM / 256, 2048 / 256), 512, 0, stream>>>(xpad, wqT, qk_b, qbuf, kbuf, ksum);
    rope_z_kernel     <<<MM / 32,                    256, 0, stream>>>(qbuf, kbuf, ksum, krP, zbuf);
    kv_kernel         <<<dim3(32, 16),               256, 0, stream>>>(krP, xpad, kvpart);
    kv_reduce_t_kernel<<<dim3(16, 32),               256, 0, stream>>>(kvpart, kvT);
    lepe_mfma         <<<dim3(MM / 256, CC / 256),   512, 0, stream>>>(xpad, wlT, lepe_b, qbuf, kvT, zbuf, out);
}

// Round 3
// 519.064 us; speedup vs baseline: 1.4626x; 1.0615x over previous
//
#include <hip/hip_runtime.h>
#include <cmath>

#define BB 4
#define NN 4096
#define CC 1024
#define HH 8
#define DD 128
#define MM (BB*NN)   // 16384
#define NP (NN+2)    // padded rows per batch

typedef __attribute__((ext_vector_type(8))) short bf16x8;
typedef __attribute__((ext_vector_type(4))) float f32x4;

static __device__ __forceinline__ unsigned short f2bf(float f) {
    unsigned int u = __float_as_uint(f);
    unsigned int r = (u + 0x7FFF + ((u >> 16) & 1)) >> 16;
    return (unsigned short)r;
}
static __device__ __forceinline__ float bf2f(short s) {
    return __uint_as_float(((unsigned int)(unsigned short)s) << 16);
}
static __device__ __forceinline__ float4 bf4(ushort4 u) {
    float4 f;
    f.x = __uint_as_float((unsigned int)u.x << 16);
    f.y = __uint_as_float((unsigned int)u.y << 16);
    f.z = __uint_as_float((unsigned int)u.z << 16);
    f.w = __uint_as_float((unsigned int)u.w << 16);
    return f;
}

static __device__ __forceinline__ void load_lds16(const void* g, void* l) {
    __builtin_amdgcn_global_load_lds(
        (const __attribute__((address_space(1))) unsigned int*)g,
        (__attribute__((address_space(3))) unsigned int*)l, 16, 0, 0);
}

// XOR bank swizzle for [*][64]-short tiles (128B rows, 8 x 16B slots/row):
// LDS[row][slot] holds G[row][slot ^ (row&7)]; reads apply the same XOR.
// Breaks the 16-way ds_read_b128 conflict (all lanes same 16B column) to 2-way.
static __device__ __forceinline__ int swz(int row, int ko) {
    return (row * 64 + ko) ^ ((row & 7) << 3);
}

// ---------------------------------------------------------------------------
// P1: xpad[b][p][c] (bf16), p in [0,NP): rows 0 and NP-1 zero, p = x[b][p-1]
// ---------------------------------------------------------------------------
__global__ __launch_bounds__(256) void padx_kernel(
    const float* __restrict__ x, unsigned short* __restrict__ xpad)
{
    const int r = blockIdx.x;
    const int b = r / NP, p = r % NP;
    const int c = threadIdx.x * 4;
    ushort4 v = {0, 0, 0, 0};
    if (p >= 1 && p <= NN) {
        const float4 f = *(const float4*)&x[(size_t)(b * NN + p - 1) * CC + c];
        v.x = f2bf(f.x); v.y = f2bf(f.y); v.z = f2bf(f.z); v.w = f2bf(f.w);
    }
    *(ushort4*)&xpad[(size_t)r * CC + c] = v;
}

// ---------------------------------------------------------------------------
// P2: dst[c][r] = bf16(src[r][c])
// ---------------------------------------------------------------------------
__global__ __launch_bounds__(256) void transpose_bf16_kernel(
    const float* __restrict__ src, unsigned short* __restrict__ dst,
    int R, int Cc)
{
    __shared__ float t[32][33];
    const int r0 = blockIdx.y * 32, c0 = blockIdx.x * 32;
    const int tx = threadIdx.x & 31, ty = threadIdx.x >> 5;
    #pragma unroll
    for (int i = 0; i < 4; ++i) {
        int r = ty + i * 8;
        t[r][tx] = src[(size_t)(r0 + r) * Cc + c0 + tx];
    }
    __syncthreads();
    #pragma unroll
    for (int i = 0; i < 4; ++i) {
        int r = ty + i * 8;
        dst[(size_t)(c0 + r) * R + r0 + tx] = f2bf(t[tx][r]);
    }
}

// ---------------------------------------------------------------------------
// Staging for 256x64 bf16 tiles (512 threads, 4 x 16B loads each).
// LDS dest is wave-uniform base + lane*16 (global_load_lds constraint, linear);
// the global SOURCE slot is pre-swizzled so that reads with swz() see G[row][s].
// ---------------------------------------------------------------------------
static __device__ __forceinline__ void stage_tile(
    const unsigned short* __restrict__ g, int stride,
    unsigned short* lds, int tid)
{
    const int wb = tid & ~63;   // wave-uniform
    #pragma unroll
    for (int l = 0; l < 4; ++l) {
        const int c = l * 512 + tid;
        const int row = c >> 3;
        const int col8 = (c & 7) ^ (row & 7);   // inverse swizzle on source
        load_lds16(&g[(size_t)row * stride + col8 * 8],
                   &lds[(size_t)(l * 512 + wb) * 8]);
    }
}
static __device__ __forceinline__ void stage_ab(
    const unsigned short* __restrict__ Ag, int astride,
    const unsigned short* __restrict__ Bg, int bstride,
    unsigned short* As, unsigned short* Bs, int tid)
{
    stage_tile(Ag, astride, As, tid);
    stage_tile(Bg, bstride, Bs, tid);
}

// ---------------------------------------------------------------------------
// K1: qk = x @ qk_w + qk_b ; elu+1 ; q,k stored bf16; k column sums -> ksum
// 256x256 tile, BK=64, 512 thr (8 waves, 2Mx4N), double-buffered LDS 128KB,
// 2-phase: stage(next) -> ds_read+MFMA(cur) -> __syncthreads (drains vmcnt).
// ---------------------------------------------------------------------------
__global__ __launch_bounds__(512) void gemm_qk_mfma(
    const unsigned short* __restrict__ xpad, const unsigned short* __restrict__ wT,
    const float* __restrict__ bias, unsigned short* __restrict__ qbuf,
    unsigned short* __restrict__ kbuf, float* __restrict__ ksum)
{
    __shared__ __align__(16) unsigned short As[2][16384];
    __shared__ __align__(16) unsigned short Bs[2][16384];
    const int m0 = blockIdx.x * 256;
    const int n0 = blockIdx.y * 256;
    const int tid = threadIdx.x;
    const int lane = tid & 63;
    const int wv = tid >> 6;
    const int wr = wv >> 2, wc = wv & 3;       // wave -> (M-half, N-quarter)
    const int b = m0 >> 12;
    const int rbase = m0 + 1 + 2 * b;          // padded-row base
    const int rl = lane & 15;

    f32x4 acc[8][4] = {};
    stage_ab(&xpad[(size_t)rbase * CC], CC, &wT[(size_t)n0 * CC], CC,
             As[0], Bs[0], tid);
    __syncthreads();
    for (int kt = 0; kt < 16; ++kt) {
        const int cur = kt & 1;
        if (kt + 1 < 16)
            stage_ab(&xpad[(size_t)rbase * CC + (kt + 1) * 64], CC,
                     &wT[(size_t)n0 * CC + (kt + 1) * 64], CC,
                     As[cur ^ 1], Bs[cur ^ 1], tid);
        const unsigned short* Ab = As[cur];
        const unsigned short* Bb = Bs[cur];
        #pragma unroll
        for (int ks = 0; ks < 2; ++ks) {
            const int ko = ks * 32 + (lane >> 4) * 8;
            bf16x8 af[8], bfr[4];
            #pragma unroll
            for (int mf = 0; mf < 8; ++mf)
                af[mf] = *(const bf16x8*)&Ab[swz(wr * 128 + mf * 16 + rl, ko)];
            #pragma unroll
            for (int nf = 0; nf < 4; ++nf)
                bfr[nf] = *(const bf16x8*)&Bb[swz(wc * 64 + nf * 16 + rl, ko)];
            #pragma unroll
            for (int mf = 0; mf < 8; ++mf)
                #pragma unroll
                for (int nf = 0; nf < 4; ++nf)
                    acc[mf][nf] = __builtin_amdgcn_mfma_f32_16x16x32_bf16(
                        af[mf], bfr[nf], acc[mf][nf], 0, 0, 0);
        }
        __syncthreads();   // drains vmcnt(0): next tile landed, cur free
    }
    const bool khalf = (n0 >= CC);             // block is entirely q or k half
    const int col = lane & 15, rb4 = (lane >> 4) * 4;
    #pragma unroll
    for (int nf = 0; nf < 4; ++nf) {
        const int n = n0 + wc * 64 + nf * 16 + col;
        const float bn = bias[n];
        float csum = 0.0f;
        #pragma unroll
        for (int mf = 0; mf < 8; ++mf)
            #pragma unroll
            for (int r = 0; r < 4; ++r) {
                const int m = m0 + wr * 128 + mf * 16 + rb4 + r;
                float v = acc[mf][nf][r] + bn;
                v = (v > 0.0f) ? (v + 1.0f) : expf(v);   // elu(v)+1
                csum += v;
                if (!khalf) qbuf[(size_t)m * CC + n] = f2bf(v);
                else        kbuf[(size_t)m * CC + (n - CC)] = f2bf(v);
            }
        if (khalf) atomicAdd(&ksum[b * CC + (n - CC)], csum);
    }
}

// ---------------------------------------------------------------------------
// K3: thread = (row, head). z[m,h] = 1/(dot(q_head, ksum_head)/N + 1e-6);
// RoPE q in place (barrier-ordered); kr -> krP[b][h][n][d] bf16.
// ---------------------------------------------------------------------------
__global__ __launch_bounds__(256) void rope_z_kernel(
    unsigned short* __restrict__ qbuf, const unsigned short* __restrict__ kbuf,
    const float* __restrict__ ksum, unsigned short* __restrict__ krP,
    float* __restrict__ zbuf)
{
    const int tid = threadIdx.x;
    const int row = tid >> 3;            // 0..31
    const int h = tid & 7;
    const int m = blockIdx.x * 32 + row;
    const int b = m >> 12;
    const int pos = m & (NN - 1);
    unsigned short* qrow = qbuf + (size_t)m * CC + h * DD;
    const unsigned short* krow = kbuf + (size_t)m * CC + h * DD;

    bf16x8 qv[16], kv8[16];
    #pragma unroll
    for (int i = 0; i < 16; ++i) {
        qv[i]  = *(const bf16x8*)&qrow[i * 8];
        kv8[i] = *(const bf16x8*)&krow[i * 8];
    }
    // z from pre-rope q
    const float* km = ksum + b * CC + h * DD;
    float dot = 0.0f;
    #pragma unroll
    for (int i = 0; i < 16; ++i)
        #pragma unroll
        for (int jq = 0; jq < 8; ++jq)
            dot = fmaf(bf2f(qv[i][jq]), km[i * 8 + jq], dot);
    dot *= (1.0f / (float)NN);
    __syncthreads();   // all q reads complete before in-place writes
    zbuf[(size_t)m * HH + h] = 1.0f / (dot + 1e-6f);

    #pragma unroll
    for (int c8 = 0; c8 < 8; ++c8) {
        bf16x8 qpr, qpi, kpr, kpi;
        #pragma unroll
        for (int u = 0; u < 8; ++u) {
            const int jj = c8 * 8 + u;
            const int j = h * 64 + jj;           // global pair index 0..511
            const float theta = __builtin_exp2f((float)j * (-13.287712379549449f / 512.0f));
            float sv, cv;
            __sincosf((float)pos * theta, &sv, &cv);
            const int li = c8 * 2 + (u >> 2);
            const int le = (2 * u) & 7;
            const float q0 = bf2f(qv[li][le]),  q1 = bf2f(qv[li][le + 1]);
            const float k0 = bf2f(kv8[li][le]), k1 = bf2f(kv8[li][le + 1]);
            qpr[u] = (short)f2bf(cv * q0 - sv * q1);
            qpi[u] = (short)f2bf(cv * q1 + sv * q0);
            kpr[u] = (short)f2bf(cv * k0 - sv * k1);
            kpi[u] = (short)f2bf(cv * k1 + sv * k0);
        }
        *(bf16x8*)&qbuf[(size_t)m * CC + h * 64 + c8 * 8] = qpr;
        *(bf16x8*)&qbuf[(size_t)m * CC + 512 + h * 64 + c8 * 8] = qpi;
        unsigned short* kp1 = &krP[((size_t)(b * 8 + (h >> 1)) * NN + pos) * DD + (h & 1) * 64 + c8 * 8];
        unsigned short* kp2 = &krP[((size_t)(b * 8 + 4 + (h >> 1)) * NN + pos) * DD + (h & 1) * 64 + c8 * 8];
        *(bf16x8*)kp1 = kpr;
        *(bf16x8*)kp2 = kpi;
    }
}

// ---------------------------------------------------------------------------
// K4: kvpart[slice][bh][d][e] = sum over slice's 256 n of kr[n,d]*v[n,e]
// Reg-prefetch 2-phase: next iteration's global loads issue before compute.
// ---------------------------------------------------------------------------
__global__ __launch_bounds__(256) void kv_kernel(
    const unsigned short* __restrict__ krP, const unsigned short* __restrict__ xpad,
    float* __restrict__ kvpart)
{
    __shared__ float ksm[8][132];
    __shared__ float vsm[8][132];
    const int bh = blockIdx.x;                 // 0..31
    const int slice = blockIdx.y;              // 0..15
    const int b = bh >> 3, h = bh & 7;
    const int n0 = slice * 256;
    const int tid = threadIdx.x;
    const int td = (tid >> 4) * 8;
    const int te = (tid & 15) * 8;
    const unsigned short* kp = krP + ((size_t)bh * NN + n0) * DD;
    const unsigned short* vp = xpad + ((size_t)(b * NP) + 1 + n0) * CC + h * DD;
    const int sr = tid >> 5;                   // staging row 0..7
    const int sc = (tid & 31) * 4;             // staging col
    float acc[8][8] = {};
    ushort4 kq = *(const ushort4*)&kp[(size_t)sr * DD + sc];
    ushort4 vq = *(const ushort4*)&vp[(size_t)sr * CC + sc];
    for (int r0 = 0; r0 < 256; r0 += 8) {
        *(float4*)&ksm[sr][sc] = bf4(kq);
        *(float4*)&vsm[sr][sc] = bf4(vq);
        __syncthreads();
        if (r0 + 8 < 256) {    // issue next loads; latency hides under compute
            kq = *(const ushort4*)&kp[(size_t)(r0 + 8 + sr) * DD + sc];
            vq = *(const ushort4*)&vp[(size_t)(r0 + 8 + sr) * CC + sc];
        }
        #pragma unroll
        for (int r = 0; r < 8; ++r) {
            float a[8], bv[8];
            *(float4*)&a[0]  = *(const float4*)&ksm[r][td];
            *(float4*)&a[4]  = *(const float4*)&ksm[r][td + 4];
            *(float4*)&bv[0] = *(const float4*)&vsm[r][te];
            *(float4*)&bv[4] = *(const float4*)&vsm[r][te + 4];
            #pragma unroll
            for (int i = 0; i < 8; ++i)
                #pragma unroll
                for (int j = 0; j < 8; ++j)
                    acc[i][j] = fmaf(a[i], bv[j], acc[i][j]);
        }
        __syncthreads();
    }
    float* op = kvpart + ((size_t)slice * 32 + bh) * (DD * DD);
    #pragma unroll
    for (int i = 0; i < 8; ++i)
        #pragma unroll
        for (int j = 0; j < 8; j += 4)
            *(float4*)&op[(td + i) * DD + te + j] = *(float4*)&acc[i][j];
}

// ---------------------------------------------------------------------------
// K4b: kvT[bh][e][d] = bf16( (1/64) * sum over 16 slices kvpart[sl][bh][d][e] )
// 32x32 LDS-transposed tiles; grid (16 tiles, 32 bh).
// ---------------------------------------------------------------------------
__global__ __launch_bounds__(256) void kv_reduce_t_kernel(
    const float* __restrict__ kvpart, unsigned short* __restrict__ kvT)
{
    __shared__ float t[32][33];
    const int bh = blockIdx.y;
    const int dblk = blockIdx.x >> 2, eblk = blockIdx.x & 3;
    const int tx = threadIdx.x & 31, ty = threadIdx.x >> 5;
    #pragma unroll
    for (int i = 0; i < 4; ++i) {
        const int d = dblk * 32 + ty + i * 8;
        float s = 0.0f;
        #pragma unroll
        for (int sl = 0; sl < 16; ++sl)
            s += kvpart[((size_t)sl * 32 + bh) * (DD * DD) + (size_t)d * DD + eblk * 32 + tx];
        t[ty + i * 8][tx] = s * (1.0f / 64.0f);
    }
    __syncthreads();
    #pragma unroll
    for (int i = 0; i < 4; ++i) {
        const int e = ty + i * 8;
        kvT[((size_t)bh * DD + eblk * 32 + e) * DD + dblk * 32 + tx] = f2bf(t[tx][e]);
    }
}

// ---------------------------------------------------------------------------
// K6 (fused): out = z * (qr @ kv) + conv1d(x, lepe_w, SAME) + lepe_b
// attn pre-pass: 2 K-tiles (K=128 head dim), then acc *= z; then the 48-tile
// conv loop accumulates on top. Epilogue is a pure store (no out RMW).
// ---------------------------------------------------------------------------
__global__ __launch_bounds__(512) void lepe_mfma(
    const unsigned short* __restrict__ xpad, const unsigned short* __restrict__ wT,
    const float* __restrict__ bias, const unsigned short* __restrict__ qr,
    const unsigned short* __restrict__ kvT, const float* __restrict__ z,
    float* __restrict__ out)
{
    __shared__ __align__(16) unsigned short As[2][16384];
    __shared__ __align__(16) unsigned short Bs[2][16384];
    const int m0 = blockIdx.x * 256;
    const int n0 = blockIdx.y * 256;
    const int tid = threadIdx.x;
    const int lane = tid & 63;
    const int wv = tid >> 6;
    const int wr = wv >> 2, wc = wv & 3;
    const int b = m0 >> 12;
    const int rbase = m0 + 1 + 2 * b;
    const int rl = lane & 15;
    const int rb4 = (lane >> 4) * 4;
    const int h0 = n0 >> 7;                    // first head of this n-block
    const int hw = h0 + (wc >> 1);             // wave's head (wave-uniform)

    f32x4 acc[8][4] = {};

    // ---- attn pre-pass: acc = qr(m, head cols) @ kvT^T over K=128 ----
    #pragma unroll
    for (int kt = 0; kt < 2; ++kt) {
        stage_tile(&qr[(size_t)m0 * CC + h0 * DD + kt * 64], CC, As[0], tid);
        stage_tile(&qr[(size_t)m0 * CC + (h0 + 1) * DD + kt * 64], CC, As[1], tid);
        stage_tile(&kvT[(size_t)(b * 8 + h0) * DD * DD + kt * 64], DD, Bs[0], tid);
        __syncthreads();
        const unsigned short* Ab = As[wc >> 1];
        const unsigned short* Bb = Bs[0];
        #pragma unroll
        for (int ks = 0; ks < 2; ++ks) {
            const int ko = ks * 32 + (lane >> 4) * 8;
            bf16x8 af[8], bfr[4];
            #pragma unroll
            for (int mf = 0; mf < 8; ++mf)
                af[mf] = *(const bf16x8*)&Ab[swz(wr * 128 + mf * 16 + rl, ko)];
            #pragma unroll
            for (int nf = 0; nf < 4; ++nf)
                bfr[nf] = *(const bf16x8*)&Bb[swz(wc * 64 + nf * 16 + rl, ko)];
            #pragma unroll
            for (int mf = 0; mf < 8; ++mf)
                #pragma unroll
                for (int nf = 0; nf < 4; ++nf)
                    acc[mf][nf] = __builtin_amdgcn_mfma_f32_16x16x32_bf16(
                        af[mf], bfr[nf], acc[mf][nf], 0, 0, 0);
        }
        __syncthreads();
    }

    // ---- scale attn accumulator by z[m, hw] ----
    #pragma unroll
    for (int mf = 0; mf < 8; ++mf)
        #pragma unroll
        for (int r = 0; r < 4; ++r) {
            const float zz = z[(size_t)(m0 + wr * 128 + mf * 16 + rb4 + r) * HH + hw];
            #pragma unroll
            for (int nf = 0; nf < 4; ++nf)
                acc[mf][nf][r] *= zz;
        }

    // ---- conv main loop (2-phase double-buffered) ----
    // kt=0: shift=-1, i0=0
    stage_ab(&xpad[(size_t)(rbase - 1) * CC], CC, &wT[(size_t)n0 * (3 * CC)], 3 * CC,
             As[0], Bs[0], tid);
    __syncthreads();
    for (int kt = 0; kt < 48; ++kt) {
        const int cur = kt & 1;
        if (kt + 1 < 48) {
            const int k0n = (kt + 1) * 64;
            const int sh = (k0n >> 10) - 1;
            const int i0 = k0n & (CC - 1);
            stage_ab(&xpad[(size_t)(rbase + sh) * CC + i0], CC,
                     &wT[(size_t)n0 * (3 * CC) + k0n], 3 * CC,
                     As[cur ^ 1], Bs[cur ^ 1], tid);
        }
        const unsigned short* Ab = As[cur];
        const unsigned short* Bb = Bs[cur];
        #pragma unroll
        for (int ks = 0; ks < 2; ++ks) {
            const int ko = ks * 32 + (lane >> 4) * 8;
            bf16x8 af[8], bfr[4];
            #pragma unroll
            for (int mf = 0; mf < 8; ++mf)
                af[mf] = *(const bf16x8*)&Ab[swz(wr * 128 + mf * 16 + rl, ko)];
            #pragma unroll
            for (int nf = 0; nf < 4; ++nf)
                bfr[nf] = *(const bf16x8*)&Bb[swz(wc * 64 + nf * 16 + rl, ko)];
            #pragma unroll
            for (int mf = 0; mf < 8; ++mf)
                #pragma unroll
                for (int nf = 0; nf < 4; ++nf)
                    acc[mf][nf] = __builtin_amdgcn_mfma_f32_16x16x32_bf16(
                        af[mf], bfr[nf], acc[mf][nf], 0, 0, 0);
        }
        __syncthreads();
    }

    // ---- epilogue: pure write ----
    const int col = lane & 15;
    #pragma unroll
    for (int nf = 0; nf < 4; ++nf) {
        const int n = n0 + wc * 64 + nf * 16 + col;
        const float bn = bias[n];
        #pragma unroll
        for (int mf = 0; mf < 8; ++mf)
            #pragma unroll
            for (int r = 0; r < 4; ++r) {
                const int m = m0 + wr * 128 + mf * 16 + rb4 + r;
                out[(size_t)m * CC + n] = acc[mf][nf][r] + bn;
            }
    }
}

// ---------------------------------------------------------------------------
extern "C" void kernel_launch(void* const* d_in, const int* in_sizes, int n_in,
                              void* d_out, int out_size, void* d_ws, size_t ws_size,
                              hipStream_t stream)
{
    const float* x      = (const float*)d_in[0];
    const float* qk_w   = (const float*)d_in[1];
    const float* qk_b   = (const float*)d_in[2];
    const float* lepe_w = (const float*)d_in[3];
    const float* lepe_b = (const float*)d_in[4];
    float* out = (float*)d_out;

    // fp32 region
    float* ws     = (float*)d_ws;
    float* zbuf   = ws;                                   // MM*HH
    float* ksum   = zbuf + (size_t)MM * HH;               // BB*CC
    float* kvpart = ksum + (size_t)BB * CC;               // 16*32*128*128
    // bf16 region
    unsigned short* xpad = (unsigned short*)(kvpart + (size_t)16 * 32 * DD * DD);
    unsigned short* wqT  = xpad + (size_t)BB * NP * CC;   // [2048][1024]
    unsigned short* wlT  = wqT + (size_t)2 * CC * CC;     // [1024][3072]
    unsigned short* qbuf = wlT + (size_t)CC * 3 * CC;     // M*C (q, then qr in place)
    unsigned short* kbuf = qbuf + (size_t)MM * CC;        // M*C
    unsigned short* krP  = kbuf + (size_t)MM * CC;        // [32][4096][128]
    unsigned short* kvT  = krP + (size_t)32 * NN * DD;    // [32][128e][128d]

    hipMemsetAsync(ksum, 0, BB * CC * sizeof(float), stream);

    padx_kernel          <<<BB * NP,                      256, 0, stream>>>(x, xpad);
    transpose_bf16_kernel<<<dim3(2 * CC / 32, CC / 32),   256, 0, stream>>>(qk_w, wqT, CC, 2 * CC);
    transpose_bf16_kernel<<<dim3(CC / 32, 3 * CC / 32),   256, 0, stream>>>(lepe_w, wlT, 3 * CC, CC);

    gemm_qk_mfma      <<<dim3(MM / 256, 2048 / 256), 512, 0, stream>>>(xpad, wqT, qk_b, qbuf, kbuf, ksum);
    rope_z_kernel     <<<MM / 32,                    256, 0, stream>>>(qbuf, kbuf, ksum, krP, zbuf);
    kv_kernel         <<<dim3(32, 16),               256, 0, stream>>>(krP, xpad, kvpart);
    kv_reduce_t_kernel<<<dim3(16, 32),               256, 0, stream>>>(kvpart, kvT);
    lepe_mfma         <<<dim3(MM / 256, CC / 256),   512, 0, stream>>>(xpad, wlT, lepe_b, qbuf, kvT, zbuf, out);
}

// Round 4
// 510.478 us; speedup vs baseline: 1.4872x; 1.0168x over previous
//
#include <hip/hip_runtime.h>
#include <cmath>

#define BB 4
#define NN 4096
#define CC 1024
#define HH 8
#define DD 128
#define MM (BB*NN)   // 16384
#define NP (NN+2)    // padded rows per batch

typedef __attribute__((ext_vector_type(8))) short bf16x8;
typedef __attribute__((ext_vector_type(4))) float f32x4;

static __device__ __forceinline__ unsigned short f2bf(float f) {
    unsigned int u = __float_as_uint(f);
    unsigned int r = (u + 0x7FFF + ((u >> 16) & 1)) >> 16;
    return (unsigned short)r;
}
static __device__ __forceinline__ float bf2f(short s) {
    return __uint_as_float(((unsigned int)(unsigned short)s) << 16);
}
static __device__ __forceinline__ float4 bf4(ushort4 u) {
    float4 f;
    f.x = __uint_as_float((unsigned int)u.x << 16);
    f.y = __uint_as_float((unsigned int)u.y << 16);
    f.z = __uint_as_float((unsigned int)u.z << 16);
    f.w = __uint_as_float((unsigned int)u.w << 16);
    return f;
}

static __device__ __forceinline__ void load_lds16(const void* g, void* l) {
    __builtin_amdgcn_global_load_lds(
        (const __attribute__((address_space(1))) unsigned int*)g,
        (__attribute__((address_space(3))) unsigned int*)l, 16, 0, 0);
}

// XOR bank swizzle for [*][64]-short tiles (128B rows, 8 x 16B slots/row):
// LDS[row][slot] holds G[row][slot ^ (row&7)]; reads apply the same XOR.
static __device__ __forceinline__ int swz(int row, int ko) {
    return (row * 64 + ko) ^ ((row & 7) << 3);
}

// Compiler-level memory fence (zero instructions): stops hipcc from moving
// LDS/global ops across raw s_barrier (rule #18-style insurance).
#define CFENCE() asm volatile("" ::: "memory")

// ---------------------------------------------------------------------------
// P1: xpad[b][p][c] (bf16), p in [0,NP): rows 0 and NP-1 zero, p = x[b][p-1]
// ---------------------------------------------------------------------------
__global__ __launch_bounds__(256) void padx_kernel(
    const float* __restrict__ x, unsigned short* __restrict__ xpad)
{
    const int r = blockIdx.x;
    const int b = r / NP, p = r % NP;
    const int c = threadIdx.x * 4;
    ushort4 v = {0, 0, 0, 0};
    if (p >= 1 && p <= NN) {
        const float4 f = *(const float4*)&x[(size_t)(b * NN + p - 1) * CC + c];
        v.x = f2bf(f.x); v.y = f2bf(f.y); v.z = f2bf(f.z); v.w = f2bf(f.w);
    }
    *(ushort4*)&xpad[(size_t)r * CC + c] = v;
}

// ---------------------------------------------------------------------------
// P2: dst[c][r] = bf16(src[r][c])
// ---------------------------------------------------------------------------
__global__ __launch_bounds__(256) void transpose_bf16_kernel(
    const float* __restrict__ src, unsigned short* __restrict__ dst,
    int R, int Cc)
{
    __shared__ float t[32][33];
    const int r0 = blockIdx.y * 32, c0 = blockIdx.x * 32;
    const int tx = threadIdx.x & 31, ty = threadIdx.x >> 5;
    #pragma unroll
    for (int i = 0; i < 4; ++i) {
        int r = ty + i * 8;
        t[r][tx] = src[(size_t)(r0 + r) * Cc + c0 + tx];
    }
    __syncthreads();
    #pragma unroll
    for (int i = 0; i < 4; ++i) {
        int r = ty + i * 8;
        dst[(size_t)(c0 + r) * R + r0 + tx] = f2bf(t[tx][r]);
    }
}

// ---------------------------------------------------------------------------
// Staging for 256x64 bf16 tiles (512 threads, 4 x 16B loads each).
// LDS dest is wave-uniform base + lane*16 (global_load_lds constraint, linear);
// the global SOURCE slot is pre-swizzled so that reads with swz() see G[row][s].
// ---------------------------------------------------------------------------
static __device__ __forceinline__ void stage_tile(
    const unsigned short* __restrict__ g, int stride,
    unsigned short* lds, int tid)
{
    const int wb = tid & ~63;   // wave-uniform
    #pragma unroll
    for (int l = 0; l < 4; ++l) {
        const int c = l * 512 + tid;
        const int row = c >> 3;
        const int col8 = (c & 7) ^ (row & 7);   // inverse swizzle on source
        load_lds16(&g[(size_t)row * stride + col8 * 8],
                   &lds[(size_t)(l * 512 + wb) * 8]);
    }
}
static __device__ __forceinline__ void stage_ab(
    const unsigned short* __restrict__ Ag, int astride,
    const unsigned short* __restrict__ Bg, int bstride,
    unsigned short* As, unsigned short* Bs, int tid)
{
    stage_tile(Ag, astride, As, tid);
    stage_tile(Bg, bstride, Bs, tid);
}

// One BK=64 K-tile of MFMAs for a wave's 128x64 sub-tile (swizzled reads).
static __device__ __forceinline__ void mfma_tile(
    const unsigned short* __restrict__ Ab, const unsigned short* __restrict__ Bb,
    int wr, int wc, int lane, f32x4 acc[8][4])
{
    const int rl = lane & 15;
    __builtin_amdgcn_s_setprio(1);
    #pragma unroll
    for (int ks = 0; ks < 2; ++ks) {
        const int ko = ks * 32 + (lane >> 4) * 8;
        bf16x8 af[8], bfr[4];
        #pragma unroll
        for (int mf = 0; mf < 8; ++mf)
            af[mf] = *(const bf16x8*)&Ab[swz(wr * 128 + mf * 16 + rl, ko)];
        #pragma unroll
        for (int nf = 0; nf < 4; ++nf)
            bfr[nf] = *(const bf16x8*)&Bb[swz(wc * 64 + nf * 16 + rl, ko)];
        #pragma unroll
        for (int mf = 0; mf < 8; ++mf)
            #pragma unroll
            for (int nf = 0; nf < 4; ++nf)
                acc[mf][nf] = __builtin_amdgcn_mfma_f32_16x16x32_bf16(
                    af[mf], bfr[nf], acc[mf][nf], 0, 0, 0);
    }
    __builtin_amdgcn_s_setprio(0);
}

// ---------------------------------------------------------------------------
// K1: qk = x @ qk_w + qk_b ; elu+1 ; q,k stored bf16; k column sums -> ksum
// 256x256 tile, BK=64, 8 waves. Counted-vmcnt 2-phase (T4): stage(next) ->
// s_waitcnt vmcnt(8) [own cur-tile loads landed] -> s_barrier -> MFMA(cur) ->
// s_barrier. Next tile's 8 loads stay in flight across the compute phase.
// ---------------------------------------------------------------------------
__global__ __launch_bounds__(512) void gemm_qk_mfma(
    const unsigned short* __restrict__ xpad, const unsigned short* __restrict__ wT,
    const float* __restrict__ bias, unsigned short* __restrict__ qbuf,
    unsigned short* __restrict__ kbuf, float* __restrict__ ksum)
{
    __shared__ __align__(16) unsigned short As[2][16384];
    __shared__ __align__(16) unsigned short Bs[2][16384];
    const int m0 = blockIdx.x * 256;
    const int n0 = blockIdx.y * 256;
    const int tid = threadIdx.x;
    const int lane = tid & 63;
    const int wv = tid >> 6;
    const int wr = wv >> 2, wc = wv & 3;       // wave -> (M-half, N-quarter)
    const int b = m0 >> 12;
    const int rbase = m0 + 1 + 2 * b;          // padded-row base

    f32x4 acc[8][4] = {};
    stage_ab(&xpad[(size_t)rbase * CC], CC, &wT[(size_t)n0 * CC], CC,
             As[0], Bs[0], tid);
    for (int kt = 0; kt < 16; ++kt) {
        const int cur = kt & 1;
        if (kt + 1 < 16) {
            stage_ab(&xpad[(size_t)rbase * CC + (kt + 1) * 64], CC,
                     &wT[(size_t)n0 * CC + (kt + 1) * 64], CC,
                     As[cur ^ 1], Bs[cur ^ 1], tid);
            asm volatile("s_waitcnt vmcnt(8)" ::: "memory");
        } else {
            asm volatile("s_waitcnt vmcnt(0)" ::: "memory");
        }
        __builtin_amdgcn_s_barrier();          // all waves: cur tile ready
        CFENCE();
        mfma_tile(As[cur], Bs[cur], wr, wc, lane, acc);
        CFENCE();
        __builtin_amdgcn_s_barrier();          // all waves done reading cur
    }
    const bool khalf = (n0 >= CC);             // block is entirely q or k half
    const int col = lane & 15, rb4 = (lane >> 4) * 4;
    #pragma unroll
    for (int nf = 0; nf < 4; ++nf) {
        const int n = n0 + wc * 64 + nf * 16 + col;
        const float bn = bias[n];
        float csum = 0.0f;
        #pragma unroll
        for (int mf = 0; mf < 8; ++mf)
            #pragma unroll
            for (int r = 0; r < 4; ++r) {
                const int m = m0 + wr * 128 + mf * 16 + rb4 + r;
                float v = acc[mf][nf][r] + bn;
                v = (v > 0.0f) ? (v + 1.0f) : __expf(v);   // elu(v)+1
                csum += v;
                if (!khalf) qbuf[(size_t)m * CC + n] = f2bf(v);
                else        kbuf[(size_t)m * CC + (n - CC)] = f2bf(v);
            }
        if (khalf) atomicAdd(&ksum[b * CC + (n - CC)], csum);
    }
}

// ---------------------------------------------------------------------------
// K3: thread = (row, head). z[m,h] = 1/(dot(q_head, ksum_head)/N + 1e-6);
// RoPE q in place (barrier-ordered); kr -> krP[b][h][n][d] bf16.
// ---------------------------------------------------------------------------
__global__ __launch_bounds__(256) void rope_z_kernel(
    unsigned short* __restrict__ qbuf, const unsigned short* __restrict__ kbuf,
    const float* __restrict__ ksum, unsigned short* __restrict__ krP,
    float* __restrict__ zbuf)
{
    const int tid = threadIdx.x;
    const int row = tid >> 3;            // 0..31
    const int h = tid & 7;
    const int m = blockIdx.x * 32 + row;
    const int b = m >> 12;
    const int pos = m & (NN - 1);
    unsigned short* qrow = qbuf + (size_t)m * CC + h * DD;
    const unsigned short* krow = kbuf + (size_t)m * CC + h * DD;

    bf16x8 qv[16], kv8[16];
    #pragma unroll
    for (int i = 0; i < 16; ++i) {
        qv[i]  = *(const bf16x8*)&qrow[i * 8];
        kv8[i] = *(const bf16x8*)&krow[i * 8];
    }
    // z from pre-rope q
    const float* km = ksum + b * CC + h * DD;
    float dot = 0.0f;
    #pragma unroll
    for (int i = 0; i < 16; ++i)
        #pragma unroll
        for (int jq = 0; jq < 8; ++jq)
            dot = fmaf(bf2f(qv[i][jq]), km[i * 8 + jq], dot);
    dot *= (1.0f / (float)NN);
    __syncthreads();   // all q reads complete before in-place writes
    zbuf[(size_t)m * HH + h] = 1.0f / (dot + 1e-6f);

    #pragma unroll
    for (int c8 = 0; c8 < 8; ++c8) {
        bf16x8 qpr, qpi, kpr, kpi;
        #pragma unroll
        for (int u = 0; u < 8; ++u) {
            const int jj = c8 * 8 + u;
            const int j = h * 64 + jj;           // global pair index 0..511
            const float theta = __builtin_exp2f((float)j * (-13.287712379549449f / 512.0f));
            float sv, cv;
            __sincosf((float)pos * theta, &sv, &cv);
            const int li = c8 * 2 + (u >> 2);
            const int le = (2 * u) & 7;
            const float q0 = bf2f(qv[li][le]),  q1 = bf2f(qv[li][le + 1]);
            const float k0 = bf2f(kv8[li][le]), k1 = bf2f(kv8[li][le + 1]);
            qpr[u] = (short)f2bf(cv * q0 - sv * q1);
            qpi[u] = (short)f2bf(cv * q1 + sv * q0);
            kpr[u] = (short)f2bf(cv * k0 - sv * k1);
            kpi[u] = (short)f2bf(cv * k1 + sv * k0);
        }
        *(bf16x8*)&qbuf[(size_t)m * CC + h * 64 + c8 * 8] = qpr;
        *(bf16x8*)&qbuf[(size_t)m * CC + 512 + h * 64 + c8 * 8] = qpi;
        unsigned short* kp1 = &krP[((size_t)(b * 8 + (h >> 1)) * NN + pos) * DD + (h & 1) * 64 + c8 * 8];
        unsigned short* kp2 = &krP[((size_t)(b * 8 + 4 + (h >> 1)) * NN + pos) * DD + (h & 1) * 64 + c8 * 8];
        *(bf16x8*)kp1 = kpr;
        *(bf16x8*)kp2 = kpi;
    }
}

// ---------------------------------------------------------------------------
// K4: kvpart[slice][bh][d][e] = sum over slice's 256 n of kr[n,d]*v[n,e]
// Reg-prefetch 2-phase: next iteration's global loads issue before compute.
// ---------------------------------------------------------------------------
__global__ __launch_bounds__(256) void kv_kernel(
    const unsigned short* __restrict__ krP, const unsigned short* __restrict__ xpad,
    float* __restrict__ kvpart)
{
    __shared__ float ksm[8][132];
    __shared__ float vsm[8][132];
    const int bh = blockIdx.x;                 // 0..31
    const int slice = blockIdx.y;              // 0..15
    const int b = bh >> 3, h = bh & 7;
    const int n0 = slice * 256;
    const int tid = threadIdx.x;
    const int td = (tid >> 4) * 8;
    const int te = (tid & 15) * 8;
    const unsigned short* kp = krP + ((size_t)bh * NN + n0) * DD;
    const unsigned short* vp = xpad + ((size_t)(b * NP) + 1 + n0) * CC + h * DD;
    const int sr = tid >> 5;                   // staging row 0..7
    const int sc = (tid & 31) * 4;             // staging col
    float acc[8][8] = {};
    ushort4 kq = *(const ushort4*)&kp[(size_t)sr * DD + sc];
    ushort4 vq = *(const ushort4*)&vp[(size_t)sr * CC + sc];
    for (int r0 = 0; r0 < 256; r0 += 8) {
        *(float4*)&ksm[sr][sc] = bf4(kq);
        *(float4*)&vsm[sr][sc] = bf4(vq);
        __syncthreads();
        if (r0 + 8 < 256) {    // issue next loads; latency hides under compute
            kq = *(const ushort4*)&kp[(size_t)(r0 + 8 + sr) * DD + sc];
            vq = *(const ushort4*)&vp[(size_t)(r0 + 8 + sr) * CC + sc];
        }
        #pragma unroll
        for (int r = 0; r < 8; ++r) {
            float a[8], bv[8];
            *(float4*)&a[0]  = *(const float4*)&ksm[r][td];
            *(float4*)&a[4]  = *(const float4*)&ksm[r][td + 4];
            *(float4*)&bv[0] = *(const float4*)&vsm[r][te];
            *(float4*)&bv[4] = *(const float4*)&vsm[r][te + 4];
            #pragma unroll
            for (int i = 0; i < 8; ++i)
                #pragma unroll
                for (int j = 0; j < 8; ++j)
                    acc[i][j] = fmaf(a[i], bv[j], acc[i][j]);
        }
        __syncthreads();
    }
    float* op = kvpart + ((size_t)slice * 32 + bh) * (DD * DD);
    #pragma unroll
    for (int i = 0; i < 8; ++i)
        #pragma unroll
        for (int j = 0; j < 8; j += 4)
            *(float4*)&op[(td + i) * DD + te + j] = *(float4*)&acc[i][j];
}

// ---------------------------------------------------------------------------
// K4b: kvT[bh][e][d] = bf16( (1/64) * sum over 16 slices kvpart[sl][bh][d][e] )
// ---------------------------------------------------------------------------
__global__ __launch_bounds__(256) void kv_reduce_t_kernel(
    const float* __restrict__ kvpart, unsigned short* __restrict__ kvT)
{
    __shared__ float t[32][33];
    const int bh = blockIdx.y;
    const int dblk = blockIdx.x >> 2, eblk = blockIdx.x & 3;
    const int tx = threadIdx.x & 31, ty = threadIdx.x >> 5;
    #pragma unroll
    for (int i = 0; i < 4; ++i) {
        const int d = dblk * 32 + ty + i * 8;
        float s = 0.0f;
        #pragma unroll
        for (int sl = 0; sl < 16; ++sl)
            s += kvpart[((size_t)sl * 32 + bh) * (DD * DD) + (size_t)d * DD + eblk * 32 + tx];
        t[ty + i * 8][tx] = s * (1.0f / 64.0f);
    }
    __syncthreads();
    #pragma unroll
    for (int i = 0; i < 4; ++i) {
        const int e = ty + i * 8;
        kvT[((size_t)bh * DD + eblk * 32 + e) * DD + dblk * 32 + tx] = f2bf(t[tx][e]);
    }
}

// ---------------------------------------------------------------------------
// K6 (fused): out = z * (qr @ kv) + conv1d(x, lepe_w, SAME) + lepe_b
// attn pre-pass (plain 2-phase, 2 tiles), z-scale, then 48-tile conv loop
// with counted-vmcnt pipeline. Epilogue is a pure store (no out RMW).
// ---------------------------------------------------------------------------
__global__ __launch_bounds__(512) void lepe_mfma(
    const unsigned short* __restrict__ xpad, const unsigned short* __restrict__ wT,
    const float* __restrict__ bias, const unsigned short* __restrict__ qr,
    const unsigned short* __restrict__ kvT, const float* __restrict__ z,
    float* __restrict__ out)
{
    __shared__ __align__(16) unsigned short As[2][16384];
    __shared__ __align__(16) unsigned short Bs[2][16384];
    const int m0 = blockIdx.x * 256;
    const int n0 = blockIdx.y * 256;
    const int tid = threadIdx.x;
    const int lane = tid & 63;
    const int wv = tid >> 6;
    const int wr = wv >> 2, wc = wv & 3;
    const int b = m0 >> 12;
    const int rbase = m0 + 1 + 2 * b;
    const int rb4 = (lane >> 4) * 4;
    const int h0 = n0 >> 7;                    // first head of this n-block
    const int hw = h0 + (wc >> 1);             // wave's head (wave-uniform)

    f32x4 acc[8][4] = {};

    // ---- attn pre-pass: acc = qr(m, head cols) @ kvT^T over K=128 ----
    #pragma unroll
    for (int kt = 0; kt < 2; ++kt) {
        stage_tile(&qr[(size_t)m0 * CC + h0 * DD + kt * 64], CC, As[0], tid);
        stage_tile(&qr[(size_t)m0 * CC + (h0 + 1) * DD + kt * 64], CC, As[1], tid);
        stage_tile(&kvT[(size_t)(b * 8 + h0) * DD * DD + kt * 64], DD, Bs[0], tid);
        __syncthreads();
        mfma_tile(As[wc >> 1], Bs[0], wr, wc, lane, acc);
        __syncthreads();
    }

    // ---- scale attn accumulator by z[m, hw] ----
    #pragma unroll
    for (int mf = 0; mf < 8; ++mf)
        #pragma unroll
        for (int r = 0; r < 4; ++r) {
            const float zz = z[(size_t)(m0 + wr * 128 + mf * 16 + rb4 + r) * HH + hw];
            #pragma unroll
            for (int nf = 0; nf < 4; ++nf)
                acc[mf][nf][r] *= zz;
        }
    // clean vmcnt baseline: no z-loads may remain outstanding in the loop
    asm volatile("s_waitcnt vmcnt(0)" ::: "memory");

    // ---- conv main loop (counted-vmcnt 2-phase) ----
    // kt=0: shift=-1, i0=0
    stage_ab(&xpad[(size_t)(rbase - 1) * CC], CC, &wT[(size_t)n0 * (3 * CC)], 3 * CC,
             As[0], Bs[0], tid);
    for (int kt = 0; kt < 48; ++kt) {
        const int cur = kt & 1;
        if (kt + 1 < 48) {
            const int k0n = (kt + 1) * 64;
            const int sh = (k0n >> 10) - 1;
            const int i0 = k0n & (CC - 1);
            stage_ab(&xpad[(size_t)(rbase + sh) * CC + i0], CC,
                     &wT[(size_t)n0 * (3 * CC) + k0n], 3 * CC,
                     As[cur ^ 1], Bs[cur ^ 1], tid);
            asm volatile("s_waitcnt vmcnt(8)" ::: "memory");
        } else {
            asm volatile("s_waitcnt vmcnt(0)" ::: "memory");
        }
        __builtin_amdgcn_s_barrier();
        CFENCE();
        mfma_tile(As[cur], Bs[cur], wr, wc, lane, acc);
        CFENCE();
        __builtin_amdgcn_s_barrier();
    }

    // ---- epilogue: pure write ----
    const int col = lane & 15;
    #pragma unroll
    for (int nf = 0; nf < 4; ++nf) {
        const int n = n0 + wc * 64 + nf * 16 + col;
        const float bn = bias[n];
        #pragma unroll
        for (int mf = 0; mf < 8; ++mf)
            #pragma unroll
            for (int r = 0; r < 4; ++r) {
                const int m = m0 + wr * 128 + mf * 16 + rb4 + r;
                out[(size_t)m * CC + n] = acc[mf][nf][r] + bn;
            }
    }
}

// ---------------------------------------------------------------------------
extern "C" void kernel_launch(void* const* d_in, const int* in_sizes, int n_in,
                              void* d_out, int out_size, void* d_ws, size_t ws_size,
                              hipStream_t stream)
{
    const float* x      = (const float*)d_in[0];
    const float* qk_w   = (const float*)d_in[1];
    const float* qk_b   = (const float*)d_in[2];
    const float* lepe_w = (const float*)d_in[3];
    const float* lepe_b = (const float*)d_in[4];
    float* out = (float*)d_out;

    // fp32 region
    float* ws     = (float*)d_ws;
    float* zbuf   = ws;                                   // MM*HH
    float* ksum   = zbuf + (size_t)MM * HH;               // BB*CC
    float* kvpart = ksum + (size_t)BB * CC;               // 16*32*128*128
    // bf16 region
    unsigned short* xpad = (unsigned short*)(kvpart + (size_t)16 * 32 * DD * DD);
    unsigned short* wqT  = xpad + (size_t)BB * NP * CC;   // [2048][1024]
    unsigned short* wlT  = wqT + (size_t)2 * CC * CC;     // [1024][3072]
    unsigned short* qbuf = wlT + (size_t)CC * 3 * CC;     // M*C (q, then qr in place)
    unsigned short* kbuf = qbuf + (size_t)MM * CC;        // M*C
    unsigned short* krP  = kbuf + (size_t)MM * CC;        // [32][4096][128]
    unsigned short* kvT  = krP + (size_t)32 * NN * DD;    // [32][128e][128d]

    hipMemsetAsync(ksum, 0, BB * CC * sizeof(float), stream);

    padx_kernel          <<<BB * NP,                      256, 0, stream>>>(x, xpad);
    transpose_bf16_kernel<<<dim3(2 * CC / 32, CC / 32),   256, 0, stream>>>(qk_w, wqT, CC, 2 * CC);
    transpose_bf16_kernel<<<dim3(CC / 32, 3 * CC / 32),   256, 0, stream>>>(lepe_w, wlT, 3 * CC, CC);

    gemm_qk_mfma      <<<dim3(MM / 256, 2048 / 256), 512, 0, stream>>>(xpad, wqT, qk_b, qbuf, kbuf, ksum);
    rope_z_kernel     <<<MM / 32,                    256, 0, stream>>>(qbuf, kbuf, ksum, krP, zbuf);
    kv_kernel         <<<dim3(32, 16),               256, 0, stream>>>(krP, xpad, kvpart);
    kv_reduce_t_kernel<<<dim3(16, 32),               256, 0, stream>>>(kvpart, kvT);
    lepe_mfma         <<<dim3(MM / 256, CC / 256),   512, 0, stream>>>(xpad, wlT, lepe_b, qbuf, kvT, zbuf, out);
}